// Round 2
// baseline (344.528 us; speedup 1.0000x reference)
//
#include <hip/hip_runtime.h>
#include <hip/hip_fp16.h>

#define BATCH 8
#define CSTRIDE 16          // pad counters: one counter per 64B line (kills same-line atomic serialization)

typedef _Float16 h2 __attribute__((ext_vector_type(2)));

// ---------- prep: fx8[node] = 8 x f16 tanh(values[b*N+node]); zero padded counters ----------
__global__ __launch_bounds__(256) void prep_kernel(
        const float* __restrict__ values, uint4* __restrict__ fx8,
        int* __restrict__ cnt, int N)
{
    int i = blockIdx.x * 256 + threadIdx.x;
    for (int z = i; z < N * CSTRIDE; z += gridDim.x * 256) cnt[z] = 0;
    if (i >= N) return;
    uint h[8];
#pragma unroll
    for (int b = 0; b < BATCH; ++b) {
        float x = values[(long)b * N + i];
        h[b] = (uint)__half_as_ushort(__float2half(tanhf(x)));
    }
    uint4 v = { h[0] | (h[1] << 16), h[2] | (h[3] << 16),
                h[4] | (h[5] << 16), h[6] | (h[7] << 16) };
    fx8[i] = v;
}

// ---------- fill: bucket-CSR build. entry = (partner idx:16 | w as f16:16) ----------
// pos via int32 atomicAdd on line-padded counters; fixed CAP buckets (overflow
// entries dropped -- CAP=288 > max degree ~261 for Binomial(2e6, 1e-4), P~4e-6).
__global__ __launch_bounds__(256) void fill_kernel(
        const int* __restrict__ key,   // bucket key stream (tgt for pass1, src for pass2)
        const int* __restrict__ val,   // stored partner stream
        const float* __restrict__ w,
        uint* __restrict__ csr, int* __restrict__ cnt,
        int E, int CAP)
{
    int t = blockIdx.x * 256 + threadIdx.x;
    int e0 = t * 4;
    if (e0 >= E) return;
    if (e0 + 4 <= E) {
        int4 k4 = *(const int4*)(key + e0);
        int4 v4 = *(const int4*)(val + e0);
        float4 w4 = *(const float4*)(w + e0);
        int   kk[4] = { k4.x, k4.y, k4.z, k4.w };
        int   vv[4] = { v4.x, v4.y, v4.z, v4.w };
        float ww[4] = { w4.x, w4.y, w4.z, w4.w };
#pragma unroll
        for (int j = 0; j < 4; ++j) {
            int p = atomicAdd(cnt + (long)kk[j] * CSTRIDE, 1);
            uint ent = (uint)(vv[j] & 0xffff) |
                       ((uint)__half_as_ushort(__float2half(ww[j])) << 16);
            if (p < CAP) csr[(long)kk[j] * CAP + p] = ent;
        }
    } else {
        for (int e = e0; e < E; ++e) {
            int p = atomicAdd(cnt + (long)key[e] * CSTRIDE, 1);
            uint ent = (uint)(val[e] & 0xffff) |
                       ((uint)__half_as_ushort(__float2half(w[e])) << 16);
            if (p < CAP) csr[(long)key[e] * CAP + p] = ent;
        }
    }
}

// ---------- gather: one wave per node, atomic-free, f32 register accumulation ----------
// PASS1: pred_i = sum w_e * fx[src_e]  -> pred, err, err8 (packed f16)
// PASS2: aggr_j = sum w_e * err[tgt_e] -> dx = err - (1 - tanh^2) * aggr
template<int PASS>
__global__ __launch_bounds__(512) void gather_kernel(
        const uint4* __restrict__ tab,   // fx8 (PASS1) / err8 (PASS2), 16B = 8 batches
        const uint*  __restrict__ csr,
        int* __restrict__ cnt,
        const float* __restrict__ values,
        float* __restrict__ pred, float* __restrict__ err,
        float* __restrict__ dx, uint4* __restrict__ err8,
        int N, int CAP)
{
    const int lane = threadIdx.x & 63;
    const int node = blockIdx.x * 8 + (threadIdx.x >> 6);
    if (node >= N) return;
    int c = cnt[(long)node * CSTRIDE];
    if (PASS == 1 && lane == 0) cnt[(long)node * CSTRIDE] = 0;   // re-zero for fill2
    if (c > CAP) c = CAP;
    const uint* __restrict__ row = csr + (long)node * CAP;
    float a[8] = {0.f, 0.f, 0.f, 0.f, 0.f, 0.f, 0.f, 0.f};
    for (int j = lane; j < c; j += 64) {
        uint ent = row[j];                     // coalesced 256B per wave-instr
        uint4 f = tab[ent & 0xffffu];          // 16B random gather, L2-resident table
        float wv = __half2float(__ushort_as_half((ushort)(ent >> 16)));
        uint q[4] = { f.x, f.y, f.z, f.w };
#pragma unroll
        for (int p = 0; p < 4; ++p) {
            a[2 * p]     += wv * __half2float(__ushort_as_half((ushort)(q[p] & 0xffffu)));
            a[2 * p + 1] += wv * __half2float(__ushort_as_half((ushort)(q[p] >> 16)));
        }
    }
#pragma unroll
    for (int m = 32; m; m >>= 1) {
#pragma unroll
        for (int b = 0; b < 8; ++b) a[b] += __shfl_xor(a[b], m);
    }
    if (lane == 0) {
        if (PASS == 1) {
            uint h[8];
#pragma unroll
            for (int b = 0; b < 8; ++b) {
                long o = (long)b * N + node;
                float x = values[o];
                float e = x - a[b];
                pred[o] = a[b];
                err[o]  = e;
                h[b] = (uint)__half_as_ushort(__float2half(e));
            }
            uint4 v = { h[0] | (h[1] << 16), h[2] | (h[3] << 16),
                        h[4] | (h[5] << 16), h[6] | (h[7] << 16) };
            err8[node] = v;
        } else {
#pragma unroll
            for (int b = 0; b < 8; ++b) {
                long o = (long)b * N + node;
                float x = values[o];
                float f = tanhf(x);
                dx[o] = err[o] - (1.0f - f * f) * a[b];
            }
        }
    }
}

extern "C" void kernel_launch(void* const* d_in, const int* in_sizes, int n_in,
                              void* d_out, int out_size, void* d_ws, size_t ws_size,
                              hipStream_t stream)
{
    const float* values  = (const float*)d_in[0];   // [B*N]
    const float* weights = (const float*)d_in[1];   // [E]
    const int*   idx     = (const int*)d_in[2];     // [2,E] (int32 under jax defaults)

    const int BN = in_sizes[0];        // 80000
    const int E  = in_sizes[1];        // 2,000,000
    const int N  = BN / BATCH;         // 10000

    float* out  = (float*)d_out;       // [3, B*N]
    float* pred = out;
    float* err  = out + BN;
    float* dx   = out + 2 * BN;

    // workspace: fx8 uint4[N] | err8 uint4[N] | cnt int[N*CSTRIDE] | csr uint[N*CAP]
    auto al = [](size_t x) { return (x + 255) & ~(size_t)255; };
    char* ws = (char*)d_ws;
    uint4* fx8  = (uint4*)ws;
    size_t off  = al((size_t)N * 16);
    uint4* err8 = (uint4*)(ws + off);
    off += al((size_t)N * 16);
    int*   cnt  = (int*)(ws + off);
    off += al((size_t)N * CSTRIDE * 4);
    int CAP = 288;   // > max degree (~261); shrink only if workspace is tight
    while (CAP > 64 && off + (size_t)N * CAP * 4 > ws_size) CAP -= 16;
    uint* csr = (uint*)(ws + off);

    int pgrid = (N + 255) / 256;
    int fgrid = ((E + 3) / 4 + 255) / 256;
    int ggrid = (N + 7) / 8;

    // pass 1: buckets keyed by tgt (scatter axis), storing src (gather axis)
    prep_kernel<<<pgrid, 256, 0, stream>>>(values, fx8, cnt, N);
    fill_kernel<<<fgrid, 256, 0, stream>>>(idx + E, idx, weights, csr, cnt, E, CAP);
    gather_kernel<1><<<ggrid, 512, 0, stream>>>(fx8, csr, cnt, values,
                                                pred, err, dx, err8, N, CAP);
    // pass 2: buckets keyed by src, storing tgt
    fill_kernel<<<fgrid, 256, 0, stream>>>(idx, idx + E, weights, csr, cnt, E, CAP);
    gather_kernel<2><<<ggrid, 512, 0, stream>>>(err8, csr, cnt, values,
                                                pred, err, dx, err8, N, CAP);
}

// Round 3
// 175.659 us; speedup vs baseline: 1.9613x; 1.9613x over previous
//
#include <hip/hip_runtime.h>

#define BATCH 8
#define NN 10000      // nodes per graph (N)
#define STB 512       // scatter block size (40KB LDS -> 4 blocks/CU capacity)

typedef _Float16 h2 __attribute__((ext_vector_type(2)));

// Packed 2xf16 LDS atomic add (ds_pk_add_f16): one atomic covers TWO batches.
__device__ __forceinline__ void lds_pk_add(h2* p, h2 v) {
    __builtin_amdgcn_ds_atomic_fadd_v2f16(
        (__attribute__((address_space(3))) h2*)p, v);
}

// prep: fx2[bp*N + t] = { tanh(values[2bp*N+t]), tanh(values[(2bp+1)*N+t]) }
__global__ __launch_bounds__(256) void prep_kernel(
        const float* __restrict__ values, h2* __restrict__ fx2, int N)
{
    int i = blockIdx.x * 256 + threadIdx.x;
    if (i >= 4 * N) return;
    int bp = i / N, t = i - bp * N;
    float a = values[(long)(2 * bp) * N + t];
    float b = values[(long)(2 * bp + 1) * N + t];
    h2 f = { (_Float16)tanhf(a), (_Float16)tanhf(b) };
    fx2[i] = f;
}

// Scatter: block (chunk k, batch-pair bp). Gather g2[bp*N + gi] (4B global,
// L1/L2-resident, VMEM pipe); pk-atomic into h2 LDS accumulator (DS pipe).
// K=128 -> 512 blocks = 2/CU resident (16 waves/CU): probes whether the
// ~3.6 cyc/lane-visit DS-atomic law at 8 waves/CU was latency-limited.
__global__ __launch_bounds__(STB, 8) void scatter_kernel(
        const h2* __restrict__ g2,       // [4*N] packed gather values
        const float* __restrict__ w,     // [E]
        const int* __restrict__ idx,     // [2,E]
        h2* __restrict__ partial,
        int E, int N, int chunk, long goff, long soff)
{
    __shared__ alignas(16) h2 acc2[NN];
    const int k = blockIdx.x, bp = blockIdx.y;
    const h2* __restrict__ gb = g2 + (long)bp * N;

    int n4 = N >> 2;                       // N % 4 == 0
    int4* az = (int4*)acc2;
    for (int i = threadIdx.x; i < n4; i += STB) az[i] = make_int4(0, 0, 0, 0);
    __syncthreads();

    long e0 = (long)k * chunk, e1 = e0 + chunk;
    if (e0 > E) e0 = E;
    if (e1 > E) e1 = E;
    long n = e1 - e0;
    long nv8 = n >> 3;                     // 8-edge groups
    const int4*   g4p = (const int4*)(idx + goff + e0);
    const int4*   s4p = (const int4*)(idx + soff + e0);
    const float4* w4p = (const float4*)(w + e0);

    for (long v = threadIdx.x; v < nv8; v += STB) {
        int4 giA = g4p[2 * v], giB = g4p[2 * v + 1];
        int4 siA = s4p[2 * v], siB = s4p[2 * v + 1];
        float4 wvA = w4p[2 * v], wvB = w4p[2 * v + 1];
        // 8 independent VMEM gathers in flight
        h2 fA0 = gb[giA.x], fA1 = gb[giA.y], fA2 = gb[giA.z], fA3 = gb[giA.w];
        h2 fB0 = gb[giB.x], fB1 = gb[giB.y], fB2 = gb[giB.z], fB3 = gb[giB.w];
        h2 wA0 = { (_Float16)wvA.x, (_Float16)wvA.x };
        h2 wA1 = { (_Float16)wvA.y, (_Float16)wvA.y };
        h2 wA2 = { (_Float16)wvA.z, (_Float16)wvA.z };
        h2 wA3 = { (_Float16)wvA.w, (_Float16)wvA.w };
        h2 wB0 = { (_Float16)wvB.x, (_Float16)wvB.x };
        h2 wB1 = { (_Float16)wvB.y, (_Float16)wvB.y };
        h2 wB2 = { (_Float16)wvB.z, (_Float16)wvB.z };
        h2 wB3 = { (_Float16)wvB.w, (_Float16)wvB.w };
        lds_pk_add(&acc2[siA.x], wA0 * fA0);
        lds_pk_add(&acc2[siA.y], wA1 * fA1);
        lds_pk_add(&acc2[siA.z], wA2 * fA2);
        lds_pk_add(&acc2[siA.w], wA3 * fA3);
        lds_pk_add(&acc2[siB.x], wB0 * fB0);
        lds_pk_add(&acc2[siB.y], wB1 * fB1);
        lds_pk_add(&acc2[siB.z], wB2 * fB2);
        lds_pk_add(&acc2[siB.w], wB3 * fB3);
    }
    for (long e = (nv8 << 3) + threadIdx.x; e < n; e += STB) {
        int gi = idx[goff + e0 + e], si = idx[soff + e0 + e];
        _Float16 wf = (_Float16)w[e0 + e];
        h2 wb = { wf, wf };
        lds_pk_add(&acc2[si], wb * gb[gi]);
    }
    __syncthreads();

    int4* pz = (int4*)(partial + ((long)k * 4 + bp) * N);
    for (int i = threadIdx.x; i < n4; i += STB) pz[i] = az[i];
}

// ---------------- reduce 1: pred, err, err2 ----------------
// 628 blocks (t-tile 64 x 4 bp), 512 thr: 16 lanes (int4 over 4 t) x 32
// k-groups x ceil(K/32) loads; log2 cross-group tree (all threads active).
__global__ __launch_bounds__(512) void reduce1_kernel(
        const h2* __restrict__ partial,
        const float* __restrict__ values,
        float* __restrict__ pred, float* __restrict__ err,
        h2* __restrict__ err2, int N, int K)
{
    __shared__ float2 sm[32][16][4];
    const int l = threadIdx.x & 15, g = threadIdx.x >> 4;
    const int bp = blockIdx.y;
    const int t = blockIdx.x * 64 + l * 4;
    float2 a0 = {0.f,0.f}, a1 = {0.f,0.f}, a2 = {0.f,0.f}, a3 = {0.f,0.f};
    const bool ok = (t + 3) < N;
    if (ok) {
        for (int kk = g; kk < K; kk += 32) {
            int4 v = *(const int4*)(partial + (long)(kk * 4 + bp) * N + t);
            h2* hp = (h2*)&v;
            a0.x += (float)hp[0].x; a0.y += (float)hp[0].y;
            a1.x += (float)hp[1].x; a1.y += (float)hp[1].y;
            a2.x += (float)hp[2].x; a2.y += (float)hp[2].y;
            a3.x += (float)hp[3].x; a3.y += (float)hp[3].y;
        }
    }
    sm[g][l][0] = a0; sm[g][l][1] = a1; sm[g][l][2] = a2; sm[g][l][3] = a3;
    __syncthreads();
#pragma unroll
    for (int s = 16; s > 0; s >>= 1) {
        if (g < s) {
#pragma unroll
            for (int j = 0; j < 4; ++j) {
                float2 o = sm[g + s][l][j];
                sm[g][l][j].x += o.x;
                sm[g][l][j].y += o.y;
            }
        }
        __syncthreads();
    }
    if (g == 0 && ok) {
        float2 b0 = sm[0][l][0], b1 = sm[0][l][1];
        float2 b2 = sm[0][l][2], b3 = sm[0][l][3];
        long j0 = (long)(2 * bp) * N + t, j1 = j0 + N;
        float4 p0 = { b0.x, b1.x, b2.x, b3.x };
        float4 p1 = { b0.y, b1.y, b2.y, b3.y };
        float4 v0 = *(const float4*)(values + j0);
        float4 v1 = *(const float4*)(values + j1);
        float4 e0 = { v0.x - p0.x, v0.y - p0.y, v0.z - p0.z, v0.w - p0.w };
        float4 e1 = { v1.x - p1.x, v1.y - p1.y, v1.z - p1.z, v1.w - p1.w };
        *(float4*)(pred + j0) = p0;
        *(float4*)(pred + j1) = p1;
        *(float4*)(err + j0) = e0;
        *(float4*)(err + j1) = e1;
        h2 pk[4] = { { (_Float16)e0.x, (_Float16)e1.x },
                     { (_Float16)e0.y, (_Float16)e1.y },
                     { (_Float16)e0.z, (_Float16)e1.z },
                     { (_Float16)e0.w, (_Float16)e1.w } };
        *(int4*)(err2 + (long)bp * N + t) = *(int4*)pk;
    }
}

// ---------------- reduce 2: dx = err - (1 - tanh^2(x)) * aggr ----------------
__global__ __launch_bounds__(512) void reduce2_kernel(
        const h2* __restrict__ partial,
        const float* __restrict__ values,
        const float* __restrict__ err,
        float* __restrict__ dx, int N, int K)
{
    __shared__ float2 sm[32][16][4];
    const int l = threadIdx.x & 15, g = threadIdx.x >> 4;
    const int bp = blockIdx.y;
    const int t = blockIdx.x * 64 + l * 4;
    float2 a0 = {0.f,0.f}, a1 = {0.f,0.f}, a2 = {0.f,0.f}, a3 = {0.f,0.f};
    const bool ok = (t + 3) < N;
    if (ok) {
        for (int kk = g; kk < K; kk += 32) {
            int4 v = *(const int4*)(partial + (long)(kk * 4 + bp) * N + t);
            h2* hp = (h2*)&v;
            a0.x += (float)hp[0].x; a0.y += (float)hp[0].y;
            a1.x += (float)hp[1].x; a1.y += (float)hp[1].y;
            a2.x += (float)hp[2].x; a2.y += (float)hp[2].y;
            a3.x += (float)hp[3].x; a3.y += (float)hp[3].y;
        }
    }
    sm[g][l][0] = a0; sm[g][l][1] = a1; sm[g][l][2] = a2; sm[g][l][3] = a3;
    __syncthreads();
#pragma unroll
    for (int s = 16; s > 0; s >>= 1) {
        if (g < s) {
#pragma unroll
            for (int j = 0; j < 4; ++j) {
                float2 o = sm[g + s][l][j];
                sm[g][l][j].x += o.x;
                sm[g][l][j].y += o.y;
            }
        }
        __syncthreads();
    }
    if (g == 0 && ok) {
        float2 b0 = sm[0][l][0], b1 = sm[0][l][1];
        float2 b2 = sm[0][l][2], b3 = sm[0][l][3];
        long j0 = (long)(2 * bp) * N + t, j1 = j0 + N;
        float4 g0 = { b0.x, b1.x, b2.x, b3.x };
        float4 g1 = { b0.y, b1.y, b2.y, b3.y };
        float4 v0 = *(const float4*)(values + j0);
        float4 v1 = *(const float4*)(values + j1);
        float4 e0 = *(const float4*)(err + j0);
        float4 e1 = *(const float4*)(err + j1);
        float4 d0, d1;
        float f;
        f = tanhf(v0.x); d0.x = e0.x - (1.0f - f * f) * g0.x;
        f = tanhf(v0.y); d0.y = e0.y - (1.0f - f * f) * g0.y;
        f = tanhf(v0.z); d0.z = e0.z - (1.0f - f * f) * g0.z;
        f = tanhf(v0.w); d0.w = e0.w - (1.0f - f * f) * g0.w;
        f = tanhf(v1.x); d1.x = e1.x - (1.0f - f * f) * g1.x;
        f = tanhf(v1.y); d1.y = e1.y - (1.0f - f * f) * g1.y;
        f = tanhf(v1.z); d1.z = e1.z - (1.0f - f * f) * g1.z;
        f = tanhf(v1.w); d1.w = e1.w - (1.0f - f * f) * g1.w;
        *(float4*)(dx + j0) = d0;
        *(float4*)(dx + j1) = d1;
    }
}

extern "C" void kernel_launch(void* const* d_in, const int* in_sizes, int n_in,
                              void* d_out, int out_size, void* d_ws, size_t ws_size,
                              hipStream_t stream) {
    const float* values  = (const float*)d_in[0];   // [B*N]
    const float* weights = (const float*)d_in[1];   // [E]
    const int*   edge_ix = (const int*)d_in[2];     // [2, E]

    const int BN = in_sizes[0];        // 80000
    const int E  = in_sizes[1];        // 2,000,000
    const int N  = BN / BATCH;         // 10000

    float* out  = (float*)d_out;       // [3, B*N]
    float* pred = out;
    float* err  = out + BN;
    float* dx   = out + 2 * BN;

    // workspace: fx2 [4N] h2 | err2 [4N] h2 | partial [K*4][N] h2
    auto align16 = [](size_t x) { return (x + 15) & ~(size_t)15; };
    char* ws = (char*)d_ws;
    h2* fx2 = (h2*)ws;
    size_t off = align16((size_t)4 * N * sizeof(h2));
    h2* err2 = (h2*)(ws + off);
    off += align16((size_t)4 * N * sizeof(h2));
    // K=128 -> sgrid 512 blocks = 2/CU resident (occupancy probe);
    // partial matrix 20.5 MB
    int K = 128;
    while (K > 16 && off + (size_t)K * 4 * N * sizeof(h2) > ws_size) K >>= 1;
    h2* partial = (h2*)(ws + off);

    int chunk = (((E + K - 1) / K) + 7) & ~7;   // multiple of 8
    int Kused = (E + chunk - 1) / chunk;

    dim3 sgrid(Kused, 4);                 // 4 batch-pairs
    dim3 rgrid((N + 63) / 64, 4);         // 628 reduce blocks

    prep_kernel<<<(4 * N + 255) / 256, 256, 0, stream>>>(values, fx2, N);
    scatter_kernel<<<sgrid, STB, 0, stream>>>(fx2, weights, edge_ix, partial,
                                              E, N, chunk, 0L, (long)E);
    reduce1_kernel<<<rgrid, 512, 0, stream>>>(partial, values, pred, err,
                                              err2, N, Kused);
    scatter_kernel<<<sgrid, STB, 0, stream>>>(err2, weights, edge_ix, partial,
                                              E, N, chunk, (long)E, 0L);
    reduce2_kernel<<<rgrid, 512, 0, stream>>>(partial, values, err, dx,
                                              N, Kused);
}

// Round 4
// 159.908 us; speedup vs baseline: 2.1545x; 1.0985x over previous
//
#include <hip/hip_runtime.h>

#define BATCH 8
#define NN 10000      // nodes per graph (N)
#define STB 192       // scatter block: 3 waves (3 private acc copies, 140KB LDS)

typedef _Float16 h2 __attribute__((ext_vector_type(2)));
typedef _Float16 h4 __attribute__((ext_vector_type(4)));

// Packed 2xf16 LDS atomic add (ds_pk_add_f16) -- loser-lane fallback only.
__device__ __forceinline__ void lds_pk_add(h2* p, h2 v) {
    __builtin_amdgcn_ds_atomic_fadd_v2f16(
        (__attribute__((address_space(3))) h2*)p, v);
}

// prep: fx2[bp*N + t] = { tanh(values[2bp*N+t]), tanh(values[(2bp+1)*N+t]) }
__global__ __launch_bounds__(256) void prep_kernel(
        const float* __restrict__ values, h2* __restrict__ fx2, int N)
{
    int i = blockIdx.x * 256 + threadIdx.x;
    if (i >= 4 * N) return;
    int bp = i / N, t = i - bp * N;
    float a = values[(long)(2 * bp) * N + t];
    float b = values[(long)(2 * bp + 1) * N + t];
    h2 f = { (_Float16)tanhf(a), (_Float16)tanhf(b) };
    fx2[i] = f;
}

// Scatter with mark-based conflict resolution:
//  - 3 waves, each with a PRIVATE h2 acc copy (no inter-wave races)
//  - shared volatile u16 mark[] detects intra-wave same-address collisions:
//    all lanes write tid to mark[si], read back; survivor lane = winner does
//    non-atomic ds_read+pk_add+ds_write; losers (~0.4/64 lanes) use ds atomic.
//    Within a wave, DS ops are in-order -> no interleave between a winner's
//    RMW and same-wave loser atomics; cross-wave mark clobbers only demote
//    winners to losers (safe: per-wave copies).
__global__ __launch_bounds__(STB) void scatter_kernel(
        const h2* __restrict__ g2,       // [4*N] packed gather values
        const float* __restrict__ w,     // [E]
        const int* __restrict__ idx,     // [2,E]
        h2* __restrict__ partial,
        int E, int N, int chunk, long goff, long soff)
{
    __shared__ __align__(16) char smem[3 * 40000 + 20000];   // 140 KB
    h2* acc = (h2*)smem;                                     // 3 x [NN] h2
    volatile unsigned short* mark = (unsigned short*)(smem + 120000);  // [NN]

    const int tid = threadIdx.x;
    const int wid = tid >> 6;
    const int k = blockIdx.x, bp = blockIdx.y;
    const h2* __restrict__ gb = g2 + (long)bp * N;
    h2* ac = acc + wid * NN;

    // zero the 3 acc copies (mark needs no init: each lane reads the address
    // it wrote in the same slot)
    int4* az = (int4*)smem;
    for (int i = tid; i < (3 * 40000) / 16; i += STB) az[i] = make_int4(0,0,0,0);
    __syncthreads();

    long e0 = (long)k * chunk, e1 = e0 + chunk;
    if (e0 > E) e0 = E;
    if (e1 > E) e1 = E;
    long n = e1 - e0;
    long nv8 = n >> 3;                     // 8-edge groups
    const int4*   g4p = (const int4*)(idx + goff + e0);
    const int4*   s4p = (const int4*)(idx + soff + e0);
    const float4* w4p = (const float4*)(w + e0);

    const unsigned short my = (unsigned short)tid;

    for (long v = tid; v < nv8; v += STB) {
        int4 giA = g4p[2 * v], giB = g4p[2 * v + 1];
        int4 siA = s4p[2 * v], siB = s4p[2 * v + 1];
        float4 wvA = w4p[2 * v], wvB = w4p[2 * v + 1];
        // 8 independent VMEM gathers in flight
        h2 fA0 = gb[giA.x], fA1 = gb[giA.y], fA2 = gb[giA.z], fA3 = gb[giA.w];
        h2 fB0 = gb[giB.x], fB1 = gb[giB.y], fB2 = gb[giB.z], fB3 = gb[giB.w];
        h2 vals[8];
        int sis[8] = { siA.x, siA.y, siA.z, siA.w, siB.x, siB.y, siB.z, siB.w };
        {
            h2 wA0 = { (_Float16)wvA.x, (_Float16)wvA.x };
            h2 wA1 = { (_Float16)wvA.y, (_Float16)wvA.y };
            h2 wA2 = { (_Float16)wvA.z, (_Float16)wvA.z };
            h2 wA3 = { (_Float16)wvA.w, (_Float16)wvA.w };
            h2 wB0 = { (_Float16)wvB.x, (_Float16)wvB.x };
            h2 wB1 = { (_Float16)wvB.y, (_Float16)wvB.y };
            h2 wB2 = { (_Float16)wvB.z, (_Float16)wvB.z };
            h2 wB3 = { (_Float16)wvB.w, (_Float16)wvB.w };
            vals[0] = wA0 * fA0; vals[1] = wA1 * fA1;
            vals[2] = wA2 * fA2; vals[3] = wA3 * fA3;
            vals[4] = wB0 * fB0; vals[5] = wB1 * fB1;
            vals[6] = wB2 * fB2; vals[7] = wB3 * fB3;
        }
#pragma unroll
        for (int j = 0; j < 8; ++j) {
            int si = sis[j];
            mark[si] = my;                       // ds_write_b16 (volatile)
            bool win = (mark[si] == my);         // ds_read_u16  (volatile)
            h2 val = vals[j];
            if (win) ac[si] = ac[si] + val;      // exclusive non-atomic RMW
            else     lds_pk_add(&ac[si], val);   // rare collision fallback
        }
    }
    for (long e = (nv8 << 3) + tid; e < n; e += STB) {
        int gi = idx[goff + e0 + e], si = idx[soff + e0 + e];
        _Float16 wf = (_Float16)w[e0 + e];
        h2 wb = { wf, wf };
        h2 val = wb * gb[gi];
        mark[si] = my;
        bool win = (mark[si] == my);
        if (win) ac[si] = ac[si] + val;
        else     lds_pk_add(&ac[si], val);
    }
    __syncthreads();

    // fold the 3 copies, write partial row (b64 granularity: h4 = 2 nodes)
    h4* a0 = (h4*)(smem);
    h4* a1 = (h4*)(smem + 40000);
    h4* a2 = (h4*)(smem + 80000);
    h4* pz = (h4*)(partial + ((long)k * 4 + bp) * N);
    for (int i = tid; i < NN / 2; i += STB) {
        h4 s = a0[i] + a1[i] + a2[i];
        pz[i] = s;
    }
}

// ---------------- reduce 1 (flat): pred, err, err2 ----------------
// one thread per (node, bp): K strided coalesced h2 loads, f32 accumulate,
// no LDS / no barriers.
__global__ __launch_bounds__(256) void reduce1_kernel(
        const h2* __restrict__ partial,
        const float* __restrict__ values,
        float* __restrict__ pred, float* __restrict__ err,
        h2* __restrict__ err2, int N, int K)
{
    int t = blockIdx.x * 256 + threadIdx.x;
    int bp = blockIdx.y;
    if (t >= N) return;
    float sx = 0.f, sy = 0.f;
    const h2* __restrict__ p = partial + (long)bp * N + t;
#pragma unroll 8
    for (int kk = 0; kk < K; ++kk) {
        h2 v = p[(long)kk * 4 * N];
        sx += (float)v.x; sy += (float)v.y;
    }
    long j0 = (long)(2 * bp) * N + t, j1 = j0 + N;
    float v0 = values[j0], v1 = values[j1];
    float e0 = v0 - sx, e1 = v1 - sy;
    pred[j0] = sx; pred[j1] = sy;
    err[j0] = e0;  err[j1] = e1;
    h2 pk = { (_Float16)e0, (_Float16)e1 };
    err2[(long)bp * N + t] = pk;
}

// ---------------- reduce 2 (flat): dx = err - (1 - tanh^2(x)) * aggr ----------------
__global__ __launch_bounds__(256) void reduce2_kernel(
        const h2* __restrict__ partial,
        const float* __restrict__ values,
        const float* __restrict__ err,
        float* __restrict__ dx, int N, int K)
{
    int t = blockIdx.x * 256 + threadIdx.x;
    int bp = blockIdx.y;
    if (t >= N) return;
    float sx = 0.f, sy = 0.f;
    const h2* __restrict__ p = partial + (long)bp * N + t;
#pragma unroll 8
    for (int kk = 0; kk < K; ++kk) {
        h2 v = p[(long)kk * 4 * N];
        sx += (float)v.x; sy += (float)v.y;
    }
    long j0 = (long)(2 * bp) * N + t, j1 = j0 + N;
    float v0 = values[j0], v1 = values[j1];
    float f0 = tanhf(v0), f1 = tanhf(v1);
    dx[j0] = err[j0] - (1.0f - f0 * f0) * sx;
    dx[j1] = err[j1] - (1.0f - f1 * f1) * sy;
}

extern "C" void kernel_launch(void* const* d_in, const int* in_sizes, int n_in,
                              void* d_out, int out_size, void* d_ws, size_t ws_size,
                              hipStream_t stream) {
    const float* values  = (const float*)d_in[0];   // [B*N]
    const float* weights = (const float*)d_in[1];   // [E]
    const int*   edge_ix = (const int*)d_in[2];     // [2, E]

    const int BN = in_sizes[0];        // 80000
    const int E  = in_sizes[1];        // 2,000,000
    const int N  = BN / BATCH;         // 10000

    float* out  = (float*)d_out;       // [3, B*N]
    float* pred = out;
    float* err  = out + BN;
    float* dx   = out + 2 * BN;

    // workspace: fx2 [4N] h2 | err2 [4N] h2 | partial [K*4][N] h2
    auto align16 = [](size_t x) { return (x + 15) & ~(size_t)15; };
    char* ws = (char*)d_ws;
    h2* fx2 = (h2*)ws;
    size_t off = align16((size_t)4 * N * sizeof(h2));
    h2* err2 = (h2*)(ws + off);
    off += align16((size_t)4 * N * sizeof(h2));
    // K=64 -> sgrid 256 blocks = 1/CU (LDS 140KB -> 1 block/CU anyway)
    int K = 64;
    while (K > 16 && off + (size_t)K * 4 * N * sizeof(h2) > ws_size) K >>= 1;
    h2* partial = (h2*)(ws + off);

    int chunk = (((E + K - 1) / K) + 7) & ~7;   // multiple of 8
    int Kused = (E + chunk - 1) / chunk;

    dim3 sgrid(Kused, 4);                 // 4 batch-pairs
    dim3 rgrid((N + 255) / 256, 4);       // flat reduce: 1 thread per (node,bp)

    prep_kernel<<<(4 * N + 255) / 256, 256, 0, stream>>>(values, fx2, N);
    scatter_kernel<<<sgrid, STB, 0, stream>>>(fx2, weights, edge_ix, partial,
                                              E, N, chunk, 0L, (long)E);
    reduce1_kernel<<<rgrid, 256, 0, stream>>>(partial, values, pred, err,
                                              err2, N, Kused);
    scatter_kernel<<<sgrid, STB, 0, stream>>>(err2, weights, edge_ix, partial,
                                              E, N, chunk, (long)E, 0L);
    reduce2_kernel<<<rgrid, 256, 0, stream>>>(partial, values, err, dx,
                                              N, Kused);
}